// Round 6
// baseline (135.002 us; speedup 1.0000x reference)
//
#include <hip/hip_runtime.h>
#include <math.h>

// ---------------- problem constants ----------------
#define NDIM 128
#define TILE 64
#define NBLOCKS 2048
#define POS_PER_BLOCK 512          // one full j-row per block: i, b constant
#define ITERS 8                    // tiles per block
#define CH 512                     // ushorts per k'-chunk: 64 pos * 8 (no pad; all ops b128)

typedef __attribute__((ext_vector_type(8)))  short  short8;   // MFMA A/B frag
typedef __attribute__((ext_vector_type(4)))  float  float4v;  // 16x16 C/D frag
typedef __attribute__((ext_vector_type(16))) float  float16;  // 32x32 C/D frag

// gfx950 packed f32x2 -> bf16x2 (RNE), single VALU instruction
__device__ __forceinline__ unsigned cvt_pk(float lo, float hi) {
    unsigned r;
    asm("v_cvt_pk_bf16_f32 %0, %1, %2" : "=v"(r) : "v"(lo), "v"(hi));
    return r;
}

// k'-space map: chunk c (0..15), elem jj (0..7) -> actual channel index.
// One lane's 8 MFMA C-regs {4lh+0..3, 8+4lh+0..3} of a 32-ch tile form one
// contiguous chunk -> phase A/C writes are single b128, conflict-free.
__device__ __forceinline__ int kmap(int c, int jj) {
    return 32 * (c >> 2) + 16 * ((c >> 1) & 1) + 4 * (c & 1) + ((jj >> 2) << 3) + (jj & 3);
}

__global__ __launch_bounds__(256, 3)
void crpb_mfma5(const float* __restrict__ gq,   // (512,3)
                const float* __restrict__ gkv,  // (4,512,3)
                const float* __restrict__ W1,   // (3,128)
                const float* __restrict__ b1,   // (128,)
                const float* __restrict__ W2,   // (128,128)
                const float* __restrict__ b2,   // (128,)
                const float* __restrict__ W3,   // (128,4)
                const float* __restrict__ b3,   // (4,)
                float* __restrict__ out)        // (16,512,512)
{
    __shared__ __align__(16) unsigned short ash[16 * CH];   // 16 KB: h1 tile, k'-chunked
    __shared__ __align__(16) unsigned short h2s[16 * CH];   // 16 KB: h2 tile, k'-chunked
    __shared__ __align__(16) float b2s[NDIM];

    const int tid   = threadIdx.x;
    const int lane  = tid & 63;
    const int w     = __builtin_amdgcn_readfirstlane(tid >> 6);
    const int l31   = lane & 31;
    const int lhalf = lane >> 5;
    const int m16   = lane & 15;
    const int q16   = lane >> 4;

    if (tid < NDIM) b2s[tid] = b2[tid];

    // wave role (phase B/C): pos-half pt = w&1; out-ch tiles ct0, ct0+1.
    // One B-frag read feeds TWO MFMAs -> phase-B LDS reads halve vs r5.
    const int pt  = w & 1;
    const int ct0 = (w >> 1) * 2;

    // ---- preload W2^T A-frags (k'-permuted), 64 VGPRs ----
    short8 a2f0[8], a2f1[8];
    #pragma unroll
    for (int ks = 0; ks < 8; ++ks) {
        const int c = 2 * ks + lhalf;
        unsigned t0[4], t1[4];
        #pragma unroll
        for (int t = 0; t < 4; ++t) {
            const int d0 = kmap(c, 2 * t), d1 = d0 + 1;
            const int e0 = ct0 * 32 + l31, e1 = e0 + 32;
            t0[t] = cvt_pk(W2[d0 * 128 + e0], W2[d1 * 128 + e0]);
            t1[t] = cvt_pk(W2[d0 * 128 + e1], W2[d1 * 128 + e1]);
        }
        __builtin_memcpy(&a2f0[ks], t0, 16);
        __builtin_memcpy(&a2f1[ks], t1, 16);
    }

    // ---- preload W3^T A-frags (k'-permuted, N padded to 16), 16 VGPRs ----
    short8 w3t[4];
    #pragma unroll
    for (int ks = 0; ks < 4; ++ks) {
        const int c = ks * 4 + q16;
        unsigned tt[4];
        #pragma unroll
        for (int t = 0; t < 4; ++t) {
            const int k0 = kmap(c, 2 * t), k1 = k0 + 1;
            const float lo = (m16 < 4) ? W3[k0 * 4 + m16] : 0.0f;
            const float hi = (m16 < 4) ? W3[k1 * 4 + m16] : 0.0f;
            tt[t] = cvt_pk(lo, hi);
        }
        __builtin_memcpy(&w3t[ks], tt, 16);
    }
    float b3v[4];
    #pragma unroll
    for (int r = 0; r < 4; ++r) b3v[r] = (q16 == 0) ? b3[r] : 0.0f;

    __syncthreads();

    // block-constant indices: one j-row per block
    const int posblock = blockIdx.x * POS_PER_BLOCK;
    const int bb = posblock >> 18;
    const int i  = (posblock >> 9) & 511;
    const float q0 = gq[i * 3 + 0], q1 = gq[i * 3 + 1], q2 = gq[i * 3 + 2];

    // loop-invariant LDS bases
    unsigned short* aw        = ash + 4 * w * CH + lane * 8;                  // phase A writes
    const unsigned short* br  = ash + lhalf * CH + (pt * 32 + l31) * 8;       // phase B reads
    unsigned short* cw        = h2s + (4 * ct0 + lhalf) * CH + (pt * 32 + l31) * 8; // C writes
    const unsigned short* dr  = h2s + q16 * CH + (w * 16 + m16) * 8;          // phase D reads

    const float* kvp0 = gkv + (size_t)((bb << 9) + lane) * 3;
    float* obase = out + (((size_t)bb) << 20) + ((size_t)i << 9) + w * 16 + m16;

    // prefetch first tile's kv
    float kv0 = kvp0[0], kv1 = kvp0[1], kv2 = kvp0[2];

    for (int it = 0; it < ITERS; ++it) {
        const int jb = it * TILE;

        // ======== phase A: features + layer 1 (VALU) -> ash, k'-chunked ========
        {
            const float d0 = q0 - kv0, d1 = q1 - kv1, d2 = q2 - kv2;
            // prefetch next tile's kv (wrap to 0 on last iter; always in-bounds)
            const float* kvn = kvp0 + ((it + 1) & 7) * (TILE * 3);
            kv0 = kvn[0]; kv1 = kvn[1]; kv2 = kvn[2];

            const float f0 = copysignf(__logf(1.0f + fabsf(d0)), d0);
            const float f1 = copysignf(__logf(1.0f + fabsf(d1)), d1);
            const float f2 = copysignf(__logf(1.0f + fabsf(d2)), d2);
            #pragma unroll
            for (int u = 0; u < 4; ++u) {
                const int c = 4 * w + u;
                unsigned pk[4];
                #pragma unroll
                for (int t = 0; t < 4; ++t) {
                    const int ch0 = kmap(c, 2 * t), ch1 = ch0 + 1;   // wave-uniform
                    float h0 = fmaf(f2, W1[256 + ch0], fmaf(f1, W1[128 + ch0],
                               fmaf(f0, W1[ch0], b1[ch0])));
                    float h1 = fmaf(f2, W1[256 + ch1], fmaf(f1, W1[128 + ch1],
                               fmaf(f0, W1[ch1], b1[ch1])));
                    pk[t] = cvt_pk(fmaxf(h0, 0.0f), fmaxf(h1, 0.0f));
                }
                short8 v; __builtin_memcpy(&v, pk, 16);
                *(short8*)(aw + u * CH) = v;        // b128, 16-B lane stride
            }
        }
        __syncthreads();   // S1: ash ready

        // ======== phase B: layer-2 MFMA; 8 reads, 16 MFMA (each read feeds 2) ========
        float16 acc0, acc1;
        #pragma unroll
        for (int qr = 0; qr < 4; ++qr) {
            float4v i0 = *(const float4v*)&b2s[ct0 * 32 + 8 * qr + 4 * lhalf];
            float4v i1 = *(const float4v*)&b2s[ct0 * 32 + 32 + 8 * qr + 4 * lhalf];
            #pragma unroll
            for (int t = 0; t < 4; ++t) { acc0[4 * qr + t] = i0[t]; acc1[4 * qr + t] = i1[t]; }
        }
        #pragma unroll
        for (int ks = 0; ks < 8; ++ks) {
            short8 bfrag = *(const short8*)(br + ks * 2 * CH);
            acc0 = __builtin_amdgcn_mfma_f32_32x32x16_bf16(a2f0[ks], bfrag, acc0, 0, 0, 0);
            acc1 = __builtin_amdgcn_mfma_f32_32x32x16_bf16(a2f1[ks], bfrag, acc1, 0, 0, 0);
        }

        // ======== phase C: relu -> packed bf16 -> h2s; 4x b128, conflict-free ========
        {
            unsigned p0[4], p1[4], p2[4], p3[4];
            #pragma unroll
            for (int t = 0; t < 4; ++t) {
                p0[t] = cvt_pk(fmaxf(acc0[2 * t], 0.f),     fmaxf(acc0[2 * t + 1], 0.f));
                p1[t] = cvt_pk(fmaxf(acc0[8 + 2 * t], 0.f), fmaxf(acc0[8 + 2 * t + 1], 0.f));
                p2[t] = cvt_pk(fmaxf(acc1[2 * t], 0.f),     fmaxf(acc1[2 * t + 1], 0.f));
                p3[t] = cvt_pk(fmaxf(acc1[8 + 2 * t], 0.f), fmaxf(acc1[8 + 2 * t + 1], 0.f));
            }
            short8 v0, v1, v2, v3;
            __builtin_memcpy(&v0, p0, 16); __builtin_memcpy(&v1, p1, 16);
            __builtin_memcpy(&v2, p2, 16); __builtin_memcpy(&v3, p3, 16);
            *(short8*)(cw + 0 * CH) = v0;   // chunk 4ct0   + lh   (acc0 regs 0-7)
            *(short8*)(cw + 2 * CH) = v1;   // chunk 4ct0+2 + lh   (acc0 regs 8-15)
            *(short8*)(cw + 4 * CH) = v2;   // chunk 4ct0+4 + lh   (acc1 regs 0-7)
            *(short8*)(cw + 6 * CH) = v3;   // chunk 4ct0+6 + lh   (acc1 regs 8-15)
        }
        __syncthreads();   // S2: h2s ready (also fences this tile's ash reads)

        // ======== phase D: layer-3 16x16x32 MFMA + store ========
        {
            float4v acc3;
            #pragma unroll
            for (int r = 0; r < 4; ++r) acc3[r] = b3v[r];
            #pragma unroll
            for (int ks = 0; ks < 4; ++ks) {
                short8 bfrag = *(const short8*)(dr + ks * 4 * CH);
                acc3 = __builtin_amdgcn_mfma_f32_16x16x32_bf16(w3t[ks], bfrag, acc3, 0, 0, 0);
            }
            if (q16 == 0) {
                #pragma unroll
                for (int r = 0; r < 4; ++r)
                    obase[(size_t)(r << 18) + jb] = acc3[r];
            }
        }
        // next phase A overwrites ash (its reads ended before S2); D's h2s reads
        // complete before next S1, which fences the next phase C writes.
    }
}

extern "C" void kernel_launch(void* const* d_in, const int* in_sizes, int n_in,
                              void* d_out, int out_size, void* d_ws, size_t ws_size,
                              hipStream_t stream) {
    const float* gq  = (const float*)d_in[0];
    const float* gkv = (const float*)d_in[1];
    const float* W1  = (const float*)d_in[2];
    const float* b1  = (const float*)d_in[3];
    const float* W2  = (const float*)d_in[4];
    const float* b2  = (const float*)d_in[5];
    const float* W3  = (const float*)d_in[6];
    const float* b3  = (const float*)d_in[7];
    float* out = (float*)d_out;

    crpb_mfma5<<<NBLOCKS, 256, 0, stream>>>(gq, gkv, W1, b1, W2, b2, W3, b3, out);
}

// Round 7
// 127.243 us; speedup vs baseline: 1.0610x; 1.0610x over previous
//
#include <hip/hip_runtime.h>
#include <math.h>

// ---------------- problem constants ----------------
#define NDIM 128
#define TILE 64
#define NBLOCKS 1024
#define THREADS 512               // 8 waves/block
#define POS_PER_BLOCK 1024        // 2 j-rows per block
#define ITERS 16                  // 64-pos tiles per block
#define CH 512                    // ushorts per k'-chunk: 64 pos * 8

typedef __attribute__((ext_vector_type(8)))  short  short8;   // MFMA A/B frag
typedef __attribute__((ext_vector_type(4)))  float  float4v;
typedef __attribute__((ext_vector_type(16))) float  float16;  // 32x32 C/D frag

// gfx950 packed f32x2 -> bf16x2 (RNE), single VALU instruction
__device__ __forceinline__ unsigned cvt_pk(float lo, float hi) {
    unsigned r;
    asm("v_cvt_pk_bf16_f32 %0, %1, %2" : "=v"(r) : "v"(lo), "v"(hi));
    return r;
}

// k'-chunk map (layer-2): chunk c (0..15), elem jj (0..7) -> channel.
// One lane's MFMA C-reg octet forms one contiguous chunk -> b128 everywhere.
__device__ __forceinline__ int kmap(int c, int jj) {
    return 32 * (c >> 2) + 16 * ((c >> 1) & 1) + 4 * (c & 1) + ((jj >> 2) << 3) + (jj & 3);
}

__global__ __launch_bounds__(512, 4)
void crpb_mfma6(const float* __restrict__ gq,   // (512,3)
                const float* __restrict__ gkv,  // (4,512,3)
                const float* __restrict__ W1,   // (3,128)
                const float* __restrict__ b1,   // (128,)
                const float* __restrict__ W2,   // (128,128)
                const float* __restrict__ b2,   // (128,)
                const float* __restrict__ W3,   // (128,4)
                const float* __restrict__ b3,   // (4,)
                float* __restrict__ out)        // (16,512,512)
{
    __shared__ __align__(16) unsigned short ash[2][16 * CH];   // 2 x 16 KB, double-buffered
    __shared__ __align__(16) float red[2][4 * 4 * 64];         // 2 x 4 KB partials [ct][o][pos]
    __shared__ __align__(16) float b2s[NDIM];

    const int tid  = threadIdx.x;
    const int lane = tid & 63;
    const int w    = __builtin_amdgcn_readfirstlane(tid >> 6);  // 0..7
    const int l31  = lane & 31;
    const int lh   = lane >> 5;

    if (tid < NDIM) b2s[tid] = b2[tid];

    // wave role: out-ch tile ct (32 chs), pos-half ph (32 positions)
    const int ct = w & 3;
    const int ph = w >> 2;

    // ---- preload W2^T A-frags (k'-permuted), 32 VGPRs ----
    short8 a2f[8];
    #pragma unroll
    for (int ks = 0; ks < 8; ++ks) {
        const int c = 2 * ks + lh;
        unsigned t0[4];
        #pragma unroll
        for (int t = 0; t < 4; ++t) {
            const int d0 = kmap(c, 2 * t), d1 = d0 + 1;
            const int e0 = ct * 32 + l31;
            t0[t] = cvt_pk(W2[d0 * 128 + e0], W2[d1 * 128 + e0]);
        }
        __builtin_memcpy(&a2f[ks], t0, 16);
    }

    // ---- preload W3 A-frags for in-register layer 3 (8 VGPRs) ----
    // layer-3 k'-map: ch(k',m) = (k'&3) + 8*((k'>>2)&1) + 4*(k'>>3) + 16m
    // (matches acc reg q=8m+jj's row (q&3)+8*(q>>2)+4lh exactly -> B-frag = relu(acc))
    short8 w3a[2];
    #pragma unroll
    for (int m = 0; m < 2; ++m) {
        unsigned tt[4];
        #pragma unroll
        for (int t = 0; t < 4; ++t) {
            const int chl = ((2 * t) & 3) + 8 * ((2 * t) >> 2) + 4 * lh + 16 * m;
            const int ch0 = ct * 32 + chl, ch1 = ch0 + 1;
            const float lo = (l31 < 4) ? W3[ch0 * 4 + l31] : 0.0f;
            const float hi = (l31 < 4) ? W3[ch1 * 4 + l31] : 0.0f;
            tt[t] = cvt_pk(lo, hi);
        }
        __builtin_memcpy(&w3a[m], tt, 16);
    }
    const float b3r = b3[(tid >> 6) & 3];   // used by reduce phase (tid<256: o = tid>>6)

    // block-constant: 1024 consecutive positions (same b, two i-rows)
    const int posblock = blockIdx.x * POS_PER_BLOCK;
    const int bb = posblock >> 18;
    const float* kvrow = gkv + (size_t)(bb << 9) * 3;

    // prefetch tile 0's q and kv
    int ii = (posblock >> 9) & 511;
    float q0 = gq[ii * 3 + 0], q1 = gq[ii * 3 + 1], q2 = gq[ii * 3 + 2];
    const float* kp = kvrow + (size_t)((posblock & 511) + lane) * 3;
    float kv0 = kp[0], kv1 = kp[1], kv2 = kp[2];

    // ======== phase A (as lambda): features + layer 1 -> ash[buf], 2 chunks/wave ========
    auto phaseA = [&](int x, int buf) {
        const float c0 = q0 - kv0, c1 = q1 - kv1, c2 = q2 - kv2;
        // prefetch tile x+1 (wrap; always in-bounds)
        const int pn = posblock + (((x + 1) & 15) << 6);
        const int iN = (pn >> 9) & 511, jN = pn & 511;
        q0 = gq[iN * 3 + 0]; q1 = gq[iN * 3 + 1]; q2 = gq[iN * 3 + 2];
        const float* kn = kvrow + (size_t)(jN + lane) * 3;
        kv0 = kn[0]; kv1 = kn[1]; kv2 = kn[2];

        const float f0 = copysignf(__logf(1.0f + fabsf(c0)), c0);
        const float f1 = copysignf(__logf(1.0f + fabsf(c1)), c1);
        const float f2 = copysignf(__logf(1.0f + fabsf(c2)), c2);
        #pragma unroll
        for (int u = 0; u < 2; ++u) {
            const int c = 2 * w + u;                       // wave-uniform chunk
            unsigned pk[4];
            #pragma unroll
            for (int t = 0; t < 4; ++t) {
                const int ch0 = kmap(c, 2 * t), ch1 = ch0 + 1;
                float h0 = fmaf(f2, W1[256 + ch0], fmaf(f1, W1[128 + ch0],
                           fmaf(f0, W1[ch0], b1[ch0])));
                float h1 = fmaf(f2, W1[256 + ch1], fmaf(f1, W1[128 + ch1],
                           fmaf(f0, W1[ch1], b1[ch1])));
                pk[t] = cvt_pk(fmaxf(h0, 0.0f), fmaxf(h1, 0.0f));
            }
            short8 v; __builtin_memcpy(&v, pk, 16);
            *(short8*)&ash[buf][c * CH + lane * 8] = v;    // b128, conflict-free
        }
    };

    phaseA(0, 0);
    __syncthreads();   // also covers b2s staging

    for (int it = 0; it < ITERS; ++it) {
        const int buf = it & 1;
        const int posbase = posblock + it * TILE;
        const int i  = (posbase >> 9) & 511;
        const int jb = posbase & 511;

        // ======== phase B: layer-2 MFMA; acc = D[ch(ct)][pos(ph)] ========
        float16 acc;
        #pragma unroll
        for (int qr = 0; qr < 4; ++qr) {
            float4v iv = *(const float4v*)&b2s[ct * 32 + 8 * qr + 4 * lh];
            #pragma unroll
            for (int t = 0; t < 4; ++t) acc[4 * qr + t] = iv[t];
        }
        const unsigned short* br = &ash[buf][lh * CH + (ph * 32 + l31) * 8];
        #pragma unroll
        for (int ks = 0; ks < 8; ++ks) {
            short8 bfrag = *(const short8*)(br + ks * 2 * CH);
            acc = __builtin_amdgcn_mfma_f32_32x32x16_bf16(a2f[ks], bfrag, acc, 0, 0, 0);
        }

        // ======== phase C': in-register relu + layer-3 MFMA + partial write ========
        {
            unsigned pk0[4], pk1[4];
            #pragma unroll
            for (int t = 0; t < 4; ++t) {
                pk0[t] = cvt_pk(fmaxf(acc[2 * t], 0.f),     fmaxf(acc[2 * t + 1], 0.f));
                pk1[t] = cvt_pk(fmaxf(acc[8 + 2 * t], 0.f), fmaxf(acc[8 + 2 * t + 1], 0.f));
            }
            short8 bm0, bm1;
            __builtin_memcpy(&bm0, pk0, 16);
            __builtin_memcpy(&bm1, pk1, 16);
            float16 p;
            #pragma unroll
            for (int r = 0; r < 16; ++r) p[r] = 0.0f;
            p = __builtin_amdgcn_mfma_f32_32x32x16_bf16(w3a[0], bm0, p, 0, 0, 0);
            p = __builtin_amdgcn_mfma_f32_32x32x16_bf16(w3a[1], bm1, p, 0, 0, 0);
            // rows o=0..3 live in regs 0..3 of lh==0 lanes; col = pos = l31
            if (lh == 0) {
                #pragma unroll
                for (int o = 0; o < 4; ++o)
                    red[buf][(ct * 4 + o) * 64 + ph * 32 + l31] = p[o];
            }
        }

        // ======== phase A for next tile (other ash buffer) ========
        if (it != ITERS - 1) phaseA(it + 1, 1 - buf);

        __syncthreads();   // single barrier/tile: fences ash[1-buf] and red[buf]

        // ======== phase R: cross-wave reduce + coalesced store (waves 0..3) ========
        if (tid < 256) {
            const int o = tid >> 6, pos = tid & 63;
            const float* rb = &red[buf][o * 64 + pos];
            const float v = b3r + rb[0] + rb[256] + rb[512] + rb[768];
            out[((size_t)((bb << 2) + o) << 18) + ((size_t)i << 9) + jb + pos] = v;
        }
    }
}

extern "C" void kernel_launch(void* const* d_in, const int* in_sizes, int n_in,
                              void* d_out, int out_size, void* d_ws, size_t ws_size,
                              hipStream_t stream) {
    const float* gq  = (const float*)d_in[0];
    const float* gkv = (const float*)d_in[1];
    const float* W1  = (const float*)d_in[2];
    const float* b1  = (const float*)d_in[3];
    const float* W2  = (const float*)d_in[4];
    const float* b2  = (const float*)d_in[5];
    const float* W3  = (const float*)d_in[6];
    const float* b3  = (const float*)d_in[7];
    float* out = (float*)d_out;

    crpb_mfma6<<<NBLOCKS, THREADS, 0, stream>>>(gq, gkv, W1, b1, W2, b2, W3, b3, out);
}

// Round 8
// 125.672 us; speedup vs baseline: 1.0742x; 1.0125x over previous
//
#include <hip/hip_runtime.h>
#include <math.h>

// ---------------- problem constants ----------------
#define NDIM 128
#define TILE 64
#define NBLOCKS 1024
#define THREADS 512               // 8 waves/block
#define POS_PER_BLOCK 1024
#define ITERS 16                  // 64-pos tiles per block
#define CH 512                    // ushorts per k'-chunk: 64 pos * 8

typedef __attribute__((ext_vector_type(8)))  short  short8;   // MFMA A/B frag
typedef __attribute__((ext_vector_type(16))) float  float16;  // 32x32 C/D frag

// gfx950 packed f32x2 -> bf16x2 (RNE), single VALU instruction
__device__ __forceinline__ unsigned cvt_pk(float lo, float hi) {
    unsigned r;
    asm("v_cvt_pk_bf16_f32 %0, %1, %2" : "=v"(r) : "v"(lo), "v"(hi));
    return r;
}

// k'-chunk map (layer-2): chunk c (0..15), elem jj (0..7) -> channel.
__device__ __forceinline__ int kmap(int c, int jj) {
    return 32 * (c >> 2) + 16 * ((c >> 1) & 1) + 4 * (c & 1) + ((jj >> 2) << 3) + (jj & 3);
}

__global__ __launch_bounds__(512, 4)
void crpb_mfma7(const float* __restrict__ gq,   // (512,3)
                const float* __restrict__ gkv,  // (4,512,3)
                const float* __restrict__ W1,   // (3,128)
                const float* __restrict__ b1,   // (128,)
                const float* __restrict__ W2,   // (128,128)
                const float* __restrict__ b2,   // (128,)
                const float* __restrict__ W3,   // (128,4)
                const float* __restrict__ b3,   // (4,)
                float* __restrict__ out)        // (16,512,512)
{
    __shared__ __align__(16) unsigned short ash[2][16 * CH];   // 2 x 16 KB, double-buffered
    __shared__ __align__(16) float red[2][4 * 4 * 64];         // 2 x 4 KB partials [ct][o][pos]

    const int tid  = threadIdx.x;
    const int lane = tid & 63;
    const int w    = __builtin_amdgcn_readfirstlane(tid >> 6);  // 0..7
    const int l31  = lane & 31;
    const int lh   = lane >> 5;

    // wave role: out-ch tile ct (32 chs), pos-half ph (32 positions)
    const int ct = w & 3;
    const int ph = w >> 2;

    // ---- persistent bias C-operands (full fp32; zero per-tile init cost) ----
    float16 b1cv, b2cv;
    #pragma unroll
    for (int q = 0; q < 16; ++q) {
        const int row = (q & 3) + 8 * (q >> 2) + 4 * lh;
        b1cv[q] = b1[ct * 32 + row];
        b2cv[q] = b2[ct * 32 + row];
    }

    // ---- layer-1 A-frag: W1 hi/lo split, K-slots (lh=0): w0h,w0l,w0h,w1h,w1l,w1h,w2h,w2l
    //      (lh=1): w2h,0,0,0,0,0,0,0.  Paired with B-slots f0h,f0h,f0l,f1h,f1h,f1l,f2h,f2h | f2l,..
    //      sum = w0*f0 + w1*f1 + w2*f2 to ~2^-17 accuracy.
    short8 w1f;
    {
        const int ch = ct * 32 + l31;
        const float w0 = W1[ch], w1v = W1[128 + ch], w2v = W1[256 + ch];
        const unsigned u0 = cvt_pk(w0, w0), u1 = cvt_pk(w1v, w1v), u2 = cvt_pk(w2v, w2v);
        const float w0h = __uint_as_float(u0 << 16);
        const float w1h = __uint_as_float(u1 << 16);
        const float w2h = __uint_as_float(u2 << 16);
        const float w0l = w0 - w0h, w1l = w1v - w1h, w2l = w2v - w2h;
        unsigned d[4];
        if (lh == 0) {
            d[0] = cvt_pk(w0h, w0l);
            d[1] = cvt_pk(w0h, w1h);
            d[2] = cvt_pk(w1l, w1h);
            d[3] = cvt_pk(w2h, w2l);
        } else {
            d[0] = cvt_pk(w2h, 0.0f);
            d[1] = 0; d[2] = 0; d[3] = 0;
        }
        __builtin_memcpy(&w1f, d, 16);
    }

    // ---- preload W2^T A-frags (k'-permuted), 32 VGPRs ----
    short8 a2f[8];
    #pragma unroll
    for (int ks = 0; ks < 8; ++ks) {
        const int c = 2 * ks + lh;
        unsigned t0[4];
        #pragma unroll
        for (int t = 0; t < 4; ++t) {
            const int d0 = kmap(c, 2 * t), d1 = d0 + 1;
            t0[t] = cvt_pk(W2[d0 * 128 + ct * 32 + l31], W2[d1 * 128 + ct * 32 + l31]);
        }
        __builtin_memcpy(&a2f[ks], t0, 16);
    }

    // ---- W3 A-frags for in-register layer 3 (8 VGPRs) ----
    short8 w3a[2];
    #pragma unroll
    for (int m = 0; m < 2; ++m) {
        unsigned tt[4];
        #pragma unroll
        for (int t = 0; t < 4; ++t) {
            const int chl = ((2 * t) & 3) + 8 * ((2 * t) >> 2) + 4 * lh + 16 * m;
            const int ch0 = ct * 32 + chl, ch1 = ch0 + 1;
            const float lo = (l31 < 4) ? W3[ch0 * 4 + l31] : 0.0f;
            const float hi = (l31 < 4) ? W3[ch1 * 4 + l31] : 0.0f;
            tt[t] = cvt_pk(lo, hi);
        }
        __builtin_memcpy(&w3a[m], tt, 16);
    }
    const float b3r = b3[(tid >> 6) & 3];   // phase R: o = tid>>6 (tid<256)

    // block-constant: 1024 consecutive positions (same b)
    const int posblock = blockIdx.x * POS_PER_BLOCK;
    const int bb = posblock >> 18;
    const float* kvrow = gkv + (size_t)(bb << 9) * 3;

    // prefetch tile 0's q and kv (position = ph*32 + l31 within tile)
    int ii = (posblock >> 9) & 511;
    float q0 = gq[ii * 3 + 0], q1 = gq[ii * 3 + 1], q2 = gq[ii * 3 + 2];
    const int pofs = ph * 32 + l31;
    const float* kp = kvrow + (size_t)((posblock & 511) + pofs) * 3;
    float kv0 = kp[0], kv1 = kp[1], kv2 = kp[2];

    // ======== phase A: features -> hi/lo B-frag -> layer-1 MFMA -> ash[buf] ========
    auto phaseA = [&](int x, int buf) {
        const float c0 = q0 - kv0, c1 = q1 - kv1, c2 = q2 - kv2;
        // prefetch tile x+1 (wrap; always in-bounds)
        const int pn = posblock + (((x + 1) & 15) << 6);
        const int iN = (pn >> 9) & 511, jN = pn & 511;
        q0 = gq[iN * 3 + 0]; q1 = gq[iN * 3 + 1]; q2 = gq[iN * 3 + 2];
        const float* kn = kvrow + (size_t)(jN + pofs) * 3;
        kv0 = kn[0]; kv1 = kn[1]; kv2 = kn[2];

        const float f0 = copysignf(__logf(1.0f + fabsf(c0)), c0);
        const float f1 = copysignf(__logf(1.0f + fabsf(c1)), c1);
        const float f2 = copysignf(__logf(1.0f + fabsf(c2)), c2);

        // hi/lo split (exact): fXh = bf16(fX), fXl = fX - fXh
        const unsigned u0 = cvt_pk(f0, f0), u1 = cvt_pk(f1, f1), u2 = cvt_pk(f2, f2);
        const float f0h = __uint_as_float(u0 << 16);
        const float f1h = __uint_as_float(u1 << 16);
        const float f2h = __uint_as_float(u2 << 16);
        const float f0l = f0 - f0h, f1l = f1 - f1h, f2l = f2 - f2h;

        unsigned d[4];
        if (lh == 0) {
            d[0] = u0;                    // (f0h, f0h)
            d[1] = cvt_pk(f0l, f1);       // (f0l, f1h)
            d[2] = cvt_pk(f1, f1l);       // (f1h, f1l)
            d[3] = u2;                    // (f2h, f2h)
        } else {
            d[0] = cvt_pk(f2l, 0.0f);     // (f2l, 0)
            d[1] = 0; d[2] = 0; d[3] = 0;
        }
        short8 bf; __builtin_memcpy(&bf, d, 16);

        // layer 1: h1 = W1e . f + b1 (C-operand), per wave: 32 ch x 32 pos
        float16 c1r = __builtin_amdgcn_mfma_f32_32x32x16_bf16(w1f, bf, b1cv, 0, 0, 0);

        // relu -> bf16 -> ash chunks (chunk = 4ct + 2m + lh), single b128 per m
        unsigned pk0[4], pk1[4];
        #pragma unroll
        for (int t = 0; t < 4; ++t) {
            pk0[t] = cvt_pk(fmaxf(c1r[2 * t], 0.f),     fmaxf(c1r[2 * t + 1], 0.f));
            pk1[t] = cvt_pk(fmaxf(c1r[8 + 2 * t], 0.f), fmaxf(c1r[8 + 2 * t + 1], 0.f));
        }
        short8 v0, v1;
        __builtin_memcpy(&v0, pk0, 16);
        __builtin_memcpy(&v1, pk1, 16);
        *(short8*)&ash[buf][(4 * ct + lh) * CH + pofs * 8]     = v0;   // m=0
        *(short8*)&ash[buf][(4 * ct + 2 + lh) * CH + pofs * 8] = v1;   // m=1
    };

    phaseA(0, 0);
    __syncthreads();

    for (int it = 0; it < ITERS; ++it) {
        const int buf = it & 1;
        const int posbase = posblock + it * TILE;
        const int i  = (posbase >> 9) & 511;
        const int jb = posbase & 511;

        // ======== phase B: layer-2 MFMA; first C-operand = persistent b2cv ========
        const unsigned short* br = &ash[buf][lh * CH + (ph * 32 + l31) * 8];
        short8 bfrag0 = *(const short8*)(br);
        float16 acc = __builtin_amdgcn_mfma_f32_32x32x16_bf16(a2f[0], bfrag0, b2cv, 0, 0, 0);
        #pragma unroll
        for (int ks = 1; ks < 8; ++ks) {
            short8 bfrag = *(const short8*)(br + ks * 2 * CH);
            acc = __builtin_amdgcn_mfma_f32_32x32x16_bf16(a2f[ks], bfrag, acc, 0, 0, 0);
        }

        // ======== phase C': in-register relu + layer-3 MFMA + partial write ========
        {
            unsigned pk0[4], pk1[4];
            #pragma unroll
            for (int t = 0; t < 4; ++t) {
                pk0[t] = cvt_pk(fmaxf(acc[2 * t], 0.f),     fmaxf(acc[2 * t + 1], 0.f));
                pk1[t] = cvt_pk(fmaxf(acc[8 + 2 * t], 0.f), fmaxf(acc[8 + 2 * t + 1], 0.f));
            }
            short8 bm0, bm1;
            __builtin_memcpy(&bm0, pk0, 16);
            __builtin_memcpy(&bm1, pk1, 16);
            float16 p;
            #pragma unroll
            for (int r = 0; r < 16; ++r) p[r] = 0.0f;
            p = __builtin_amdgcn_mfma_f32_32x32x16_bf16(w3a[0], bm0, p, 0, 0, 0);
            p = __builtin_amdgcn_mfma_f32_32x32x16_bf16(w3a[1], bm1, p, 0, 0, 0);
            if (lh == 0) {
                #pragma unroll
                for (int o = 0; o < 4; ++o)
                    red[buf][(ct * 4 + o) * 64 + ph * 32 + l31] = p[o];
            }
        }

        // ======== phase A for next tile (other ash buffer) ========
        if (it != ITERS - 1) phaseA(it + 1, 1 - buf);

        __syncthreads();   // single barrier/tile: fences ash[1-buf] and red[buf]

        // ======== phase R: cross-wave reduce + coalesced store ========
        if (tid < 256) {
            const int o = tid >> 6, pos = tid & 63;
            const float* rb = &red[buf][o * 64 + pos];
            const float v = b3r + rb[0] + rb[256] + rb[512] + rb[768];
            out[((size_t)((bb << 2) + o) << 18) + ((size_t)i << 9) + jb + pos] = v;
        }
    }
}

extern "C" void kernel_launch(void* const* d_in, const int* in_sizes, int n_in,
                              void* d_out, int out_size, void* d_ws, size_t ws_size,
                              hipStream_t stream) {
    const float* gq  = (const float*)d_in[0];
    const float* gkv = (const float*)d_in[1];
    const float* W1  = (const float*)d_in[2];
    const float* b1  = (const float*)d_in[3];
    const float* W2  = (const float*)d_in[4];
    const float* b2  = (const float*)d_in[5];
    const float* W3  = (const float*)d_in[6];
    const float* b3  = (const float*)d_in[7];
    float* out = (float*)d_out;

    crpb_mfma7<<<NBLOCKS, THREADS, 0, stream>>>(gq, gkv, W1, b1, W2, b2, W3, b3, out);
}

// Round 9
// 122.215 us; speedup vs baseline: 1.1046x; 1.0283x over previous
//
#include <hip/hip_runtime.h>
#include <math.h>

// ---------------- problem constants ----------------
#define NBLOCKS 2048
#define THREADS 256               // 4 waves/block
#define TILE 64
#define POS_PER_BLOCK 512         // one j-row per block: i, b constant
#define ITERS 8
#define CH 512                    // ushorts per k'-chunk: 64 pos * 8

typedef __attribute__((ext_vector_type(8)))  short  short8;   // MFMA A/B frag
typedef __attribute__((ext_vector_type(4)))  float  float4v;
typedef __attribute__((ext_vector_type(16))) float  float16;  // 32x32 C/D frag

// gfx950 packed f32x2 -> bf16x2 (RNE), single VALU instruction
__device__ __forceinline__ unsigned cvt_pk(float lo, float hi) {
    unsigned r;
    asm("v_cvt_pk_bf16_f32 %0, %1, %2" : "=v"(r) : "v"(lo), "v"(hi));
    return r;
}

// k'-chunk map: chunk c (0..15), elem jj (0..7) -> channel.
// chunk c = 4*tile + 2*m + lh holds ch_local = (jj&3) + 8*(jj>>2) + 4lh + 16m,
// which is exactly the 32x32 MFMA C-reg octet m of a lane -> b128 everywhere.
__device__ __forceinline__ int kmap(int c, int jj) {
    return 32 * (c >> 2) + 16 * ((c >> 1) & 1) + 4 * (c & 1) + ((jj >> 2) << 3) + (jj & 3);
}

__global__ __launch_bounds__(256, 3)
void crpb_mfma8(const float* __restrict__ gq,   // (512,3)
                const float* __restrict__ gkv,  // (4,512,3)
                const float* __restrict__ W1,   // (3,128)
                const float* __restrict__ b1,   // (128,)
                const float* __restrict__ W2,   // (128,128)
                const float* __restrict__ b2,   // (128,)
                const float* __restrict__ W3,   // (128,4)
                const float* __restrict__ b3,   // (4,)
                float* __restrict__ out)        // (16,512,512)
{
    __shared__ __align__(16) unsigned short ash[2][16 * CH];   // 2 x 16 KB h1 tile
    __shared__ __align__(16) float red[2][2 * 4 * 64];         // 2 x 2 KB partials [ct2][o][pos]
    __shared__ __align__(16) float b2s[128];

    const int tid  = threadIdx.x;
    const int lane = tid & 63;
    const int w    = __builtin_amdgcn_readfirstlane(tid >> 6);  // 0..3
    const int l31  = lane & 31;
    const int lh   = lane >> 5;

    if (tid < 128) b2s[tid] = b2[tid];

    // wave role: ch-half ct2 (64 chs = tiles 2ct2, 2ct2+1), pos-half ph
    const int ct2 = w & 1;
    const int ph  = w >> 1;
    const int pofs = ph * 32 + l31;     // this lane's position within tile

    // persistent zero C-operand (shared by layer-1 and layer-3 MFMAs)
    float16 z16;
    #pragma unroll
    for (int r = 0; r < 16; ++r) z16[r] = 0.0f;

    // ---- layer-1 A-frags, W1 hi/lo split + b1 folded into spare K-slots ----
    // lh0 slots: (w0h,w0l),(w0h,w1h),(w1l,w1h),(w2h,w2l)  <-> B: (f0h,f0h),(f0l,f1h),(f1h,f1l),(f2h,f2h)
    // lh1 slots: (w2h,b1h),(b1l,0),0,0                    <-> B: (f2l,1.0),(1.0,0),0,0
    short8 w1f[2];
    #pragma unroll
    for (int mt = 0; mt < 2; ++mt) {
        const int ch = (ct2 * 2 + mt) * 32 + l31;
        const float w0 = W1[ch], w1v = W1[128 + ch], w2v = W1[256 + ch], b1v = b1[ch];
        const float w0h = __uint_as_float(cvt_pk(w0, w0) << 16);
        const float w1h = __uint_as_float(cvt_pk(w1v, w1v) << 16);
        const float w2h = __uint_as_float(cvt_pk(w2v, w2v) << 16);
        const float b1h = __uint_as_float(cvt_pk(b1v, b1v) << 16);
        const float w0l = w0 - w0h, w1l = w1v - w1h, w2l = w2v - w2h, b1l = b1v - b1h;
        unsigned d[4];
        if (lh == 0) {
            d[0] = cvt_pk(w0h, w0l);
            d[1] = cvt_pk(w0h, w1h);
            d[2] = cvt_pk(w1l, w1h);
            d[3] = cvt_pk(w2h, w2l);
        } else {
            d[0] = cvt_pk(w2h, b1h);
            d[1] = cvt_pk(b1l, 0.0f);
            d[2] = 0; d[3] = 0;
        }
        __builtin_memcpy(&w1f[mt], d, 16);
    }

    // ---- W2^T A-frags for BOTH ch tiles of this half (64 VGPRs) ----
    short8 a2f[2][8];
    #pragma unroll
    for (int mt = 0; mt < 2; ++mt) {
        const int e = ct2 * 64 + mt * 32 + l31;
        #pragma unroll
        for (int ks = 0; ks < 8; ++ks) {
            const int c = 2 * ks + lh;
            unsigned t0[4];
            #pragma unroll
            for (int t = 0; t < 4; ++t) {
                const int d0 = kmap(c, 2 * t), d1 = d0 + 1;
                t0[t] = cvt_pk(W2[d0 * 128 + e], W2[d1 * 128 + e]);
            }
            __builtin_memcpy(&a2f[mt][ks], t0, 16);
        }
    }

    // ---- W3 A-frags: 4 frags cover this half's 64 chs (16 VGPRs) ----
    short8 w3a[2][2];
    #pragma unroll
    for (int mt = 0; mt < 2; ++mt) {
        #pragma unroll
        for (int m2 = 0; m2 < 2; ++m2) {
            unsigned tt[4];
            #pragma unroll
            for (int t = 0; t < 4; ++t) {
                const int chl = ((2 * t) & 3) + 8 * ((2 * t) >> 2) + 4 * lh + 16 * m2;
                const int ch0 = (ct2 * 2 + mt) * 32 + chl, ch1 = ch0 + 1;
                const float lo = (l31 < 4) ? W3[ch0 * 4 + l31] : 0.0f;
                const float hi = (l31 < 4) ? W3[ch1 * 4 + l31] : 0.0f;
                tt[t] = cvt_pk(lo, hi);
            }
            __builtin_memcpy(&w3a[mt][m2], tt, 16);
        }
    }
    const float b3r = b3[w];   // phase R: o = tid>>6 = w

    // block-constant: one j-row (b, i fixed)
    const int posblock = blockIdx.x * POS_PER_BLOCK;
    const int bb = posblock >> 18;
    const int i  = (posblock >> 9) & 511;
    const float q0 = gq[i * 3 + 0], q1 = gq[i * 3 + 1], q2 = gq[i * 3 + 2];
    const float* kvrow = gkv + (size_t)(bb << 9) * 3;

    // prefetch tile 0's kv
    const float* kp = kvrow + (size_t)pofs * 3;
    float kv0 = kp[0], kv1 = kp[1], kv2 = kp[2];

    // ======== phase A: features -> layer-1 MFMA x2 -> ash[buf] ========
    auto phaseA = [&](int x, int buf) {
        const float c0 = q0 - kv0, c1 = q1 - kv1, c2 = q2 - kv2;
        const float* kn = kvrow + (size_t)((((x + 1) & 7) << 6) + pofs) * 3;
        kv0 = kn[0]; kv1 = kn[1]; kv2 = kn[2];

        const float f0 = copysignf(__logf(1.0f + fabsf(c0)), c0);
        const float f1 = copysignf(__logf(1.0f + fabsf(c1)), c1);
        const float f2 = copysignf(__logf(1.0f + fabsf(c2)), c2);
        const unsigned u0 = cvt_pk(f0, f0), u2 = cvt_pk(f2, f2);
        const float f0h = __uint_as_float(u0 << 16);
        const float f1h = __uint_as_float(cvt_pk(f1, f1) << 16);
        const float f2h = __uint_as_float(u2 << 16);
        const float f0l = f0 - f0h, f1l = f1 - f1h, f2l = f2 - f2h;

        unsigned d[4];
        if (lh == 0) {
            d[0] = u0;                    // (f0h, f0h)
            d[1] = cvt_pk(f0l, f1);       // (f0l, f1h)
            d[2] = cvt_pk(f1, f1l);       // (f1h, f1l)
            d[3] = u2;                    // (f2h, f2h)
        } else {
            d[0] = cvt_pk(f2l, 1.0f);     // (f2l, 1.0)  <- 1.0 slots pick up b1
            d[1] = cvt_pk(1.0f, 0.0f);
            d[2] = 0; d[3] = 0;
        }
        short8 bf; __builtin_memcpy(&bf, d, 16);

        #pragma unroll
        for (int mt = 0; mt < 2; ++mt) {
            const int cti = ct2 * 2 + mt;
            float16 c1r = __builtin_amdgcn_mfma_f32_32x32x16_bf16(w1f[mt], bf, z16, 0, 0, 0);
            unsigned pk0[4], pk1[4];
            #pragma unroll
            for (int t = 0; t < 4; ++t) {
                pk0[t] = cvt_pk(fmaxf(c1r[2 * t], 0.f),     fmaxf(c1r[2 * t + 1], 0.f));
                pk1[t] = cvt_pk(fmaxf(c1r[8 + 2 * t], 0.f), fmaxf(c1r[8 + 2 * t + 1], 0.f));
            }
            short8 v0, v1;
            __builtin_memcpy(&v0, pk0, 16);
            __builtin_memcpy(&v1, pk1, 16);
            *(short8*)&ash[buf][(4 * cti + lh) * CH + pofs * 8]     = v0;   // m=0 octet
            *(short8*)&ash[buf][(4 * cti + 2 + lh) * CH + pofs * 8] = v1;   // m=1 octet
        }
    };

    phaseA(0, 0);
    __syncthreads();   // also fences b2s staging

    for (int it = 0; it < ITERS; ++it) {
        const int buf = it & 1;
        const int jb = it * TILE;

        // ======== phase B: layer-2; 8 B-reads feed 16 MFMAs (2 ch tiles) ========
        float16 acc0, acc1;
        #pragma unroll
        for (int qr = 0; qr < 4; ++qr) {
            float4v i0 = *(const float4v*)&b2s[(ct2 * 2 + 0) * 32 + 8 * qr + 4 * lh];
            float4v i1 = *(const float4v*)&b2s[(ct2 * 2 + 1) * 32 + 8 * qr + 4 * lh];
            #pragma unroll
            for (int t = 0; t < 4; ++t) { acc0[4 * qr + t] = i0[t]; acc1[4 * qr + t] = i1[t]; }
        }
        const unsigned short* br = &ash[buf][lh * CH + pofs * 8];
        #pragma unroll
        for (int ks = 0; ks < 8; ++ks) {
            short8 bfrag = *(const short8*)(br + ks * 2 * CH);
            acc0 = __builtin_amdgcn_mfma_f32_32x32x16_bf16(a2f[0][ks], bfrag, acc0, 0, 0, 0);
            acc1 = __builtin_amdgcn_mfma_f32_32x32x16_bf16(a2f[1][ks], bfrag, acc1, 0, 0, 0);
        }

        // ======== phase C': in-register relu + layer-3 (4 MFMAs, partial over 64 chs) ========
        {
            unsigned pa0[4], pa1[4], pb0[4], pb1[4];
            #pragma unroll
            for (int t = 0; t < 4; ++t) {
                pa0[t] = cvt_pk(fmaxf(acc0[2 * t], 0.f),     fmaxf(acc0[2 * t + 1], 0.f));
                pa1[t] = cvt_pk(fmaxf(acc0[8 + 2 * t], 0.f), fmaxf(acc0[8 + 2 * t + 1], 0.f));
                pb0[t] = cvt_pk(fmaxf(acc1[2 * t], 0.f),     fmaxf(acc1[2 * t + 1], 0.f));
                pb1[t] = cvt_pk(fmaxf(acc1[8 + 2 * t], 0.f), fmaxf(acc1[8 + 2 * t + 1], 0.f));
            }
            short8 fa0, fa1, fb0, fb1;
            __builtin_memcpy(&fa0, pa0, 16); __builtin_memcpy(&fa1, pa1, 16);
            __builtin_memcpy(&fb0, pb0, 16); __builtin_memcpy(&fb1, pb1, 16);
            float16 p;
            p = __builtin_amdgcn_mfma_f32_32x32x16_bf16(w3a[0][0], fa0, z16, 0, 0, 0);
            p = __builtin_amdgcn_mfma_f32_32x32x16_bf16(w3a[0][1], fa1, p, 0, 0, 0);
            p = __builtin_amdgcn_mfma_f32_32x32x16_bf16(w3a[1][0], fb0, p, 0, 0, 0);
            p = __builtin_amdgcn_mfma_f32_32x32x16_bf16(w3a[1][1], fb1, p, 0, 0, 0);
            if (lh == 0) {
                #pragma unroll
                for (int o = 0; o < 4; ++o)
                    red[buf][ct2 * 256 + o * 64 + pofs] = p[o];
            }
        }

        // ======== phase A for next tile (other ash buffer) ========
        if (it != ITERS - 1) phaseA(it + 1, 1 - buf);

        __syncthreads();   // single barrier/tile: fences ash[1-buf] and red[buf]

        // ======== phase R: sum 2 ct2-partials + b3, coalesced store ========
        {
            const int o = w, pos = lane;
            const float v = b3r + red[buf][o * 64 + pos] + red[buf][256 + o * 64 + pos];
            out[((size_t)((bb << 2) + o) << 18) + ((size_t)i << 9) + jb + pos] = v;
        }
    }
}

extern "C" void kernel_launch(void* const* d_in, const int* in_sizes, int n_in,
                              void* d_out, int out_size, void* d_ws, size_t ws_size,
                              hipStream_t stream) {
    const float* gq  = (const float*)d_in[0];
    const float* gkv = (const float*)d_in[1];
    const float* W1  = (const float*)d_in[2];
    const float* b1  = (const float*)d_in[3];
    const float* W2  = (const float*)d_in[4];
    const float* b2  = (const float*)d_in[5];
    const float* W3  = (const float*)d_in[6];
    const float* b3  = (const float*)d_in[7];
    float* out = (float*)d_out;

    crpb_mfma8<<<NBLOCKS, THREADS, 0, stream>>>(gq, gkv, W1, b1, W2, b2, W3, b3, out);
}